// Round 2
// baseline (197.135 us; speedup 1.0000x reference)
//
#include <hip/hip_runtime.h>
#include <hip/hip_bf16.h>

#define S_LEN 2048
#define DIM   64
#define NBH   32            // B*H
#define NQT   32            // 2048/64
#define TILE_SH 12288       // shorts per (bh,kvtile) image: Khi 4096 | Klo 4096 | Vt 4096
#define WS_NEED ((size_t)NBH * NQT * TILE_SH * sizeof(short))

typedef __attribute__((ext_vector_type(4))) float f32x4;
typedef __attribute__((ext_vector_type(8))) short s16x8;
typedef __attribute__((ext_vector_type(4))) short s16x4;

#define MFMA_B16(A,B,C) __builtin_amdgcn_mfma_f32_16x16x32_bf16(A,B,C,0,0,0)

__device__ __forceinline__ short f2bf(float x){
  union{float f;unsigned u;} v; v.f=x;
  unsigned r = v.u + 0x7FFFu + ((v.u>>16)&1u);   // RNE
  return (short)(r>>16);
}
__device__ __forceinline__ float bf2f(short s){
  union{float f;unsigned u;} v; v.u=((unsigned)(unsigned short)s)<<16;
  return v.f;
}
__device__ __forceinline__ unsigned packbf(float a, float b){
  __hip_bfloat162 h = __float22bfloat162_rn(make_float2(a, b));   // v_cvt_pk_bf16_f32
  union { __hip_bfloat162 h; unsigned u; } cv; cv.h = h; return cv.u;
}
// XOR swizzle on element bits 3..5 (b128-safe); verified 2-way max for all hot reads.
__device__ __forceinline__ int swz(int row){
  return (((row&7) ^ ((row>>2)&7)) << 3);
}

// ---------------- pre-pass: K -> (Khi,Klo), V -> V^T, bf16, pre-swizzled tile images
__global__ __launch_bounds__(256) void prep_kv(
    const float* __restrict__ K, const float* __restrict__ V, short* __restrict__ W)
{
  const int b  = blockIdx.x;          // = bh*32 + t
  const int bh = b >> 5, t = b & 31;
  const float* Kt = K + ((size_t)bh * S_LEN + t * 64) * DIM;
  const float* Vt = V + ((size_t)bh * S_LEN + t * 64) * DIM;
  short* Wt = W + (size_t)b * TILE_SH;
  const int tid = threadIdx.x;
#pragma unroll
  for (int i = 0; i < 2; ++i) {
    const int m = i * 256 + tid;      // chunk 0..511 (8 elems each)
    const int r = m >> 3, g = m & 7;
    // --- K hi/lo: image[p] = hi/lo(K[r][(p&63)^swz(r)])
    const int c0 = (g << 3) ^ swz(r);
    float x[8];
    *(f32x4*)&x[0] = *(const f32x4*)(Kt + r * DIM + c0);
    *(f32x4*)&x[4] = *(const f32x4*)(Kt + r * DIM + c0 + 4);
    s16x8 hi, lo;
#pragma unroll
    for (int j = 0; j < 8; ++j) {
      short h = f2bf(x[j]);
      hi[j] = h;
      lo[j] = f2bf(x[j] - bf2f(h));
    }
    *(s16x8*)&Wt[m * 8]        = hi;
    *(s16x8*)&Wt[4096 + m * 8] = lo;
    // --- V^T: image[p] = bf16(V[(p&63)^swz(dv)][dv]), dv = p>>6
    const int dv = r;
    const int k0 = (g << 3) ^ swz(dv);
    s16x8 vv;
#pragma unroll
    for (int j = 0; j < 8; ++j) vv[j] = f2bf(Vt[(size_t)(k0 + j) * DIM + dv]);
    *(s16x8*)&Wt[8192 + m * 8] = vv;
  }
}

// ---------------- async stage: 24KB tile image -> LDS (linear; data pre-swizzled in ws)
__device__ __forceinline__ void stage24(const short* __restrict__ src, short* dst,
                                        int w, int l) {
#pragma unroll
  for (int q = 0; q < 6; ++q) {
    const int off = (q * 4 + w) << 10;            // wave-uniform 1KB chunks
    __builtin_amdgcn_global_load_lds(
        (const __attribute__((address_space(1))) unsigned*)((const char*)src + off + l * 16),
        (__attribute__((address_space(3))) unsigned*)((char*)dst + off),
        16, 0, 0);
  }
}

// ---------------- main flash-attention kernel
__global__ __launch_bounds__(256, 4) void fattn_main(
    const float* __restrict__ Qg, float* __restrict__ Og, const short* __restrict__ W)
{
  __shared__ __attribute__((aligned(16))) short buf[2][TILE_SH];   // 48 KB dbuf

  // XCD-chunked mapping; within an XCD, big q-tiles dispatch first (load balance).
  const int bid0 = blockIdx.x;
  const int xcd = bid0 & 7, idx = bid0 >> 3;
  const int bh = (xcd << 2) + (idx >> 5);
  const int qt = 31 - (idx & 31);

  const int tid = threadIdx.x;
  const int w = tid >> 6, l = tid & 63;
  const int l15 = l & 15, lg = l >> 4;

  const short* Wb = W + (size_t)bh * NQT * TILE_SH;
  const float* Qb = Qg + (size_t)bh * S_LEN * DIM;
  float*       Ob = Og + (size_t)bh * S_LEN * DIM;

  const int qg = qt * 64 + w * 16 + l15;          // this lane's q row
  const float SC = 0.125f * 1.44269504088896f;    // (1/sqrt(64))*log2(e)

  // ---- hoist Q fragments (hi/lo split); B-frag: col=q(l15), k = lg*8 + j (+32s)
  s16x8 qh[2], ql[2];
#pragma unroll
  for (int s = 0; s < 2; ++s) {
    const float* qp = Qb + (size_t)qg * DIM + (lg << 3) + s * 32;
    float qv[8];
    *(f32x4*)&qv[0] = *(const f32x4*)qp;
    *(f32x4*)&qv[4] = *(const f32x4*)(qp + 4);
#pragma unroll
    for (int j = 0; j < 8; ++j) {
      short h = f2bf(qv[j]);
      qh[s][j] = h;
      ql[s][j] = f2bf(qv[j] - bf2f(h));
    }
  }

  f32x4 o[4];
#pragma unroll
  for (int d = 0; d < 4; ++d) o[d] = f32x4{0.f,0.f,0.f,0.f};
  float m = -INFINITY, lsum = 0.f;

  const int nt = qt + 1;
  stage24(Wb, buf[0], w, l);
  __syncthreads();                                 // vmcnt drained by compiler
  int cur = 0;

  const int src0 = l15 + ((lg & 1) << 5);          // P-shuffle source lanes
  const int src1 = src0 + 16;
  const bool hiH = (lg >= 2);

  for (int t = 0; t < nt; ++t) {
    if (t + 1 < nt) stage24(Wb + (size_t)(t + 1) * TILE_SH, buf[cur ^ 1], w, l);

    const short* bK  = buf[cur];
    const short* bKl = bK + 4096;
    const short* bVt = bK + 8192;

    // ---- QK^T (swapped: S^T = K·Q^T), hi/lo split -> ~fp32 scores
    f32x4 acc[4];
#pragma unroll
    for (int f = 0; f < 4; ++f) acc[f] = f32x4{0.f,0.f,0.f,0.f};
#pragma unroll
    for (int f = 0; f < 4; ++f) {
      const int kr = f * 16 + l15;
#pragma unroll
      for (int s = 0; s < 2; ++s) {
        const int dk = (((lg << 3) + (s << 5)) ^ swz(kr));
        s16x8 ah = *(const s16x8*)&bK [kr * DIM + dk];
        s16x8 al = *(const s16x8*)&bKl[kr * DIM + dk];
        acc[f] = MFMA_B16(ah, qh[s], acc[f]);
        acc[f] = MFMA_B16(ah, ql[s], acc[f]);
        acc[f] = MFMA_B16(al, qh[s], acc[f]);
      }
    }

    // ---- scale + causal mask (diag tile only); per-lane row max
    const bool diag = (t == qt);
    const int kv0 = t * 64;
    float pm = -INFINITY;
#pragma unroll
    for (int f = 0; f < 4; ++f)
#pragma unroll
      for (int r = 0; r < 4; ++r) {
        float zz = acc[f][r] * SC;
        if (diag && (kv0 + f * 16 + (lg << 2) + r) > qg) zz = -INFINITY;
        acc[f][r] = zz;
        pm = fmaxf(pm, zz);
      }
    pm = fmaxf(pm, __shfl_xor(pm, 16));
    pm = fmaxf(pm, __shfl_xor(pm, 32));

    // ---- online softmax, rescale only when a new max appears (T13, THR=0: exact)
    if (!__all(pm <= m)) {
      const float mn = fmaxf(m, pm);
      const float al = exp2f(m - mn);
      m = mn; lsum *= al;
#pragma unroll
      for (int d = 0; d < 4; ++d) o[d] *= al;
    }
    float rs = 0.f;
#pragma unroll
    for (int f = 0; f < 4; ++f)
#pragma unroll
      for (int r = 0; r < 4; ++r) {
        const float pv = exp2f(acc[f][r] - m);
        acc[f][r] = pv;
        rs += pv;
      }
    rs += __shfl_xor(rs, 16);
    rs += __shfl_xor(rs, 32);
    lsum += rs;

    // ---- P: C-frag -> B-frag via 4-lane shuffles (no LDS, no barrier)
    // dest lane (l15,lg) needs P[q=l15][kv=8lg+j+32s] from lane lgc=(2lg+(j>>2))&3,
    // reg f = 2s+(lg>>1), r = j&3.
    unsigned U[4][2];
#pragma unroll
    for (int f = 0; f < 4; ++f) {
      U[f][0] = packbf(acc[f][0], acc[f][1]);
      U[f][1] = packbf(acc[f][2], acc[f][3]);
    }
#pragma unroll
    for (int s = 0; s < 2; ++s) {
      unsigned a0 = __shfl(U[2*s][0], src0), a1 = __shfl(U[2*s+1][0], src0);
      unsigned b0 = __shfl(U[2*s][1], src0), b1 = __shfl(U[2*s+1][1], src0);
      unsigned c0 = __shfl(U[2*s][0], src1), c1 = __shfl(U[2*s+1][0], src1);
      unsigned d0 = __shfl(U[2*s][1], src1), d1 = __shfl(U[2*s+1][1], src1);
      union { unsigned u[4]; s16x8 v; } pb;
      pb.u[0] = hiH ? a1 : a0;
      pb.u[1] = hiH ? b1 : b0;
      pb.u[2] = hiH ? c1 : c0;
      pb.u[3] = hiH ? d1 : d0;
      const int kv8 = (lg << 3) + (s << 5);
#pragma unroll
      for (int d = 0; d < 4; ++d) {
        const int dv = d * 16 + l15;
        s16x8 vf = *(const s16x8*)&bVt[dv * DIM + (kv8 ^ swz(dv))];
        o[d] = MFMA_B16(vf, pb.v, o[d]);
      }
    }

    __syncthreads();    // drains prefetch vmcnt AFTER compute; guards dbuf reuse
    cur ^= 1;
  }

  // ---- epilogue
  const float inv = 1.0f / lsum;
#pragma unroll
  for (int d = 0; d < 4; ++d) {
    f32x4 ov;
#pragma unroll
    for (int r = 0; r < 4; ++r) ov[r] = o[d][r] * inv;
    *(f32x4*)(Ob + (size_t)qg * DIM + d * 16 + (lg << 2)) = ov;
  }
}

// ---------------- fallback (round-1 kernel, used only if ws too small) ----------------
#define QBLK  64
#define KVBLK 64
#define NPAIR (NQT/2)
#define NBLK  (NBH*NPAIR)

__global__ __launch_bounds__(256) void fattn_fb(
    const float* __restrict__ Qg, const float* __restrict__ Kg,
    const float* __restrict__ Vg, float* __restrict__ Og)
{
  __shared__ __attribute__((aligned(16))) short Khi[KVBLK*DIM];
  __shared__ __attribute__((aligned(16))) short Klo[KVBLK*DIM];
  __shared__ __attribute__((aligned(16))) short Vt [DIM*KVBLK];
  __shared__ __attribute__((aligned(16))) short Pl [4*16*KVBLK];

  int bid0 = blockIdx.x;
  int bid  = (bid0 & 7) * (NBLK/8) + (bid0 >> 3);
  int bh   = bid / NPAIR;
  int pr   = bid % NPAIR;
  const int tid = threadIdx.x;
  const int w = tid >> 6, l = tid & 63, l15 = l & 15, lg = l >> 4;
  const float* Qb = Qg + (size_t)bh * S_LEN * DIM;
  const float* Kb = Kg + (size_t)bh * S_LEN * DIM;
  const float* Vb = Vg + (size_t)bh * S_LEN * DIM;
  float*       Ob = Og + (size_t)bh * S_LEN * DIM;
  const float SC = 0.125f * 1.44269504088896f;

  for (int half = 0; half < 2; ++half) {
    const int qt = half ? (NQT - 1 - pr) : pr;
    const int qg = qt * QBLK + w * 16 + l15;
    s16x8 qh[2], ql[2];
#pragma unroll
    for (int s = 0; s < 2; ++s) {
      const float* qp = Qb + (size_t)qg * DIM + (lg << 3) + s * 32;
      float qv[8];
      *(f32x4*)&qv[0] = *(const f32x4*)qp;
      *(f32x4*)&qv[4] = *(const f32x4*)(qp + 4);
#pragma unroll
      for (int j = 0; j < 8; ++j) {
        short h = f2bf(qv[j]); qh[s][j] = h; ql[s][j] = f2bf(qv[j] - bf2f(h));
      }
    }
    f32x4 o[4];
#pragma unroll
    for (int d = 0; d < 4; ++d) o[d] = f32x4{0.f,0.f,0.f,0.f};
    float m = -INFINITY, lsum = 0.f;
    const int ntiles = qt + 1;
    for (int t = 0; t < ntiles; ++t) {
      const int kv0 = t * KVBLK;
      __syncthreads();
      {
        const int row = tid >> 4, c4 = (tid & 15) << 2;
#pragma unroll
        for (int i = 0; i < 4; ++i) {
          const int r = row + (i << 4);
          const f32x4 kv4 = *(const f32x4*)(Kb + (size_t)(kv0 + r) * DIM + c4);
          const f32x4 vv4 = *(const f32x4*)(Vb + (size_t)(kv0 + r) * DIM + c4);
          const int cs = c4 ^ swz(r);
          s16x4 kh, kl;
#pragma unroll
          for (int j = 0; j < 4; ++j) { short h = f2bf(kv4[j]); kh[j] = h; kl[j] = f2bf(kv4[j] - bf2f(h)); }
          *(s16x4*)&Khi[r * DIM + cs] = kh;
          *(s16x4*)&Klo[r * DIM + cs] = kl;
#pragma unroll
          for (int j = 0; j < 4; ++j) { const int dv = c4 + j; Vt[dv * KVBLK + (r ^ swz(dv))] = f2bf(vv4[j]); }
        }
      }
      __syncthreads();
      f32x4 acc[4];
#pragma unroll
      for (int f = 0; f < 4; ++f) acc[f] = f32x4{0.f,0.f,0.f,0.f};
#pragma unroll
      for (int f = 0; f < 4; ++f) {
        const int kr = f * 16 + l15;
#pragma unroll
        for (int s = 0; s < 2; ++s) {
          const int dk = (((lg << 3) + (s << 5)) ^ swz(kr));
          s16x8 ah = *(const s16x8*)&Khi[kr * DIM + dk];
          s16x8 al = *(const s16x8*)&Klo[kr * DIM + dk];
          acc[f] = MFMA_B16(ah, qh[s], acc[f]);
          acc[f] = MFMA_B16(ah, ql[s], acc[f]);
          acc[f] = MFMA_B16(al, qh[s], acc[f]);
        }
      }
      const bool diag = (t == qt);
      float z[4][4];
#pragma unroll
      for (int f = 0; f < 4; ++f)
#pragma unroll
        for (int r = 0; r < 4; ++r) {
          float zz = acc[f][r] * SC;
          if (diag && (kv0 + f * 16 + (lg << 2) + r) > qg) zz = -INFINITY;
          z[f][r] = zz;
        }
      float pm = z[0][0];
#pragma unroll
      for (int f = 0; f < 4; ++f)
#pragma unroll
        for (int r = 0; r < 4; ++r) pm = fmaxf(pm, z[f][r]);
      pm = fmaxf(pm, __shfl_xor(pm, 16));
      pm = fmaxf(pm, __shfl_xor(pm, 32));
      const float mn = fmaxf(m, pm);
      const float alpha = exp2f(m - mn);
      float p[4][4]; float rs = 0.f;
#pragma unroll
      for (int f = 0; f < 4; ++f)
#pragma unroll
        for (int r = 0; r < 4; ++r) { const float pv = exp2f(z[f][r] - mn); p[f][r] = pv; rs += pv; }
      rs += __shfl_xor(rs, 16);
      rs += __shfl_xor(rs, 32);
      lsum = lsum * alpha + rs;
      m = mn;
#pragma unroll
      for (int d = 0; d < 4; ++d) o[d] *= alpha;
      short* Pw = &Pl[w * 16 * KVBLK];
#pragma unroll
      for (int f = 0; f < 4; ++f) {
        s16x4 pk;
#pragma unroll
        for (int r = 0; r < 4; ++r) pk[r] = f2bf(p[f][r]);
        const int kvc = (f * 16 + (lg << 2)) ^ swz(l15);
        *(s16x4*)&Pw[l15 * KVBLK + kvc] = pk;
      }
#pragma unroll
      for (int s = 0; s < 2; ++s) {
        const int kv8 = (lg << 3) + s * 32;
        s16x8 pf = *(const s16x8*)&Pw[l15 * KVBLK + (kv8 ^ swz(l15))];
#pragma unroll
        for (int d = 0; d < 4; ++d) {
          const int dv = d * 16 + l15;
          s16x8 vf = *(const s16x8*)&Vt[dv * KVBLK + (kv8 ^ swz(dv))];
          o[d] = MFMA_B16(vf, pf, o[d]);
        }
      }
    }
    const float inv = 1.0f / lsum;
#pragma unroll
    for (int d = 0; d < 4; ++d) {
      f32x4 ov;
#pragma unroll
      for (int r = 0; r < 4; ++r) ov[r] = o[d][r] * inv;
      *(f32x4*)(Ob + (size_t)qg * DIM + d * 16 + (lg << 2)) = ov;
    }
  }
}

extern "C" void kernel_launch(void* const* d_in, const int* in_sizes, int n_in,
                              void* d_out, int out_size, void* d_ws, size_t ws_size,
                              hipStream_t stream) {
  const float* Q = (const float*)d_in[0];
  const float* K = (const float*)d_in[1];
  const float* V = (const float*)d_in[2];
  float* O = (float*)d_out;
  if (ws_size >= WS_NEED) {
    short* W = (short*)d_ws;
    prep_kv  <<<dim3(NBH * NQT), dim3(256), 0, stream>>>(K, V, W);
    fattn_main<<<dim3(NBH * NQT), dim3(256), 0, stream>>>(Q, O, W);
  } else {
    fattn_fb<<<dim3(NBLK), dim3(256), 0, stream>>>(Q, K, V, O);
  }
}

// Round 6
// 167.082 us; speedup vs baseline: 1.1799x; 1.1799x over previous
//
#include <hip/hip_runtime.h>
#include <hip/hip_bf16.h>

#define S_LEN 2048
#define DIM   64
#define NBH   32            // B*H
#define NQT   32            // kv tiles of 64
#define NQB   16            // q blocks of 128
#define TILE_SH 12288       // shorts per (bh,kvtile) image: Khi 4096 | Klo 4096 | Vt 4096
#define WS_NEED ((size_t)NBH * NQT * TILE_SH * sizeof(short))

typedef __attribute__((ext_vector_type(4))) float f32x4;
typedef __attribute__((ext_vector_type(8))) short s16x8;
typedef __attribute__((ext_vector_type(4))) short s16x4;

#define MFMA_B16(A,B,C) __builtin_amdgcn_mfma_f32_16x16x32_bf16(A,B,C,0,0,0)
#define EX2(x) __builtin_amdgcn_exp2f(x)

__device__ __forceinline__ short f2bf(float x){
  union{float f;unsigned u;} v; v.f=x;
  unsigned r = v.u + 0x7FFFu + ((v.u>>16)&1u);   // RNE
  return (short)(r>>16);
}
__device__ __forceinline__ float bf2f(short s){
  union{float f;unsigned u;} v; v.u=((unsigned)(unsigned short)s)<<16;
  return v.f;
}
__device__ __forceinline__ unsigned packbf(float a, float b){
  __hip_bfloat162 h = __float22bfloat162_rn(make_float2(a, b));   // v_cvt_pk_bf16_f32
  union { __hip_bfloat162 h; unsigned u; } cv; cv.h = h; return cv.u;
}
// XOR swizzle on element bits 3..5 (b128-safe)
__device__ __forceinline__ int swz(int row){
  return (((row&7) ^ ((row>>2)&7)) << 3);
}

// ---------------- pre-pass: K -> (Khi,Klo), V -> V^T, bf16, pre-swizzled tile images
__global__ __launch_bounds__(256) void prep_kv(
    const float* __restrict__ K, const float* __restrict__ V, short* __restrict__ W)
{
  __shared__ short Vl[4096];          // bf16 V^T image staging (8 KB)
  const int b  = blockIdx.x;          // = bh*32 + t
  const int bh = b >> 5, t = b & 31;
  const float* Kt = K + ((size_t)bh * S_LEN + t * 64) * DIM;
  const float* Vt = V + ((size_t)bh * S_LEN + t * 64) * DIM;
  short* Wt = W + (size_t)b * TILE_SH;
  const int tid = threadIdx.x;

  // --- K hi/lo: image[p] = hi/lo(K[r][(p&63)^swz(r)]) — coalesced f32x4 reads
#pragma unroll
  for (int i = 0; i < 2; ++i) {
    const int m = i * 256 + tid;      // chunk 0..511 (8 elems each)
    const int r = m >> 3, g = m & 7;
    const int c0 = (g << 3) ^ swz(r);
    float x[8];
    *(f32x4*)&x[0] = *(const f32x4*)(Kt + r * DIM + c0);
    *(f32x4*)&x[4] = *(const f32x4*)(Kt + r * DIM + c0 + 4);
    s16x8 hi, lo;
#pragma unroll
    for (int j = 0; j < 8; ++j) {
      short h = f2bf(x[j]);
      hi[j] = h;
      lo[j] = f2bf(x[j] - bf2f(h));
    }
    *(s16x8*)&Wt[m * 8]        = hi;
    *(s16x8*)&Wt[4096 + m * 8] = lo;
  }

  // --- V: coalesced row reads -> LDS transpose (image layout) -> coalesced out
  {
    const int r = tid >> 2;                 // 0..63 (row of V)
    const int cb = (tid & 3) << 4;          // 16-col chunk
    float x[16];
#pragma unroll
    for (int q = 0; q < 4; ++q)
      *(f32x4*)&x[q * 4] = *(const f32x4*)(Vt + r * DIM + cb + q * 4);
#pragma unroll
    for (int j = 0; j < 16; ++j) {
      const int c = cb + j;                 // = dv
      Vl[c * 64 + (r ^ swz(c))] = f2bf(x[j]);   // image[dv*64+y] = V[y^swz(dv)][dv]
    }
  }
  __syncthreads();
#pragma unroll
  for (int i = 0; i < 2; ++i) {
    const int p = (i * 256 + tid) * 8;
    *(s16x8*)&Wt[8192 + p] = *(const s16x8*)&Vl[p];
  }
}

// ---------------- async stage: 24KB tile image -> LDS (linear; data pre-swizzled in ws)
__device__ __forceinline__ void stage24(const short* __restrict__ src, short* dst,
                                        int w, int l) {
#pragma unroll
  for (int q = 0; q < 3; ++q) {
    const int off = (q * 8 + w) << 10;            // 24 × 1KB chunks, 8 waves
    __builtin_amdgcn_global_load_lds(
        (const __attribute__((address_space(1))) unsigned*)((const char*)src + off + l * 16),
        (__attribute__((address_space(3))) unsigned*)((char*)dst + off),
        16, 0, 0);
  }
}

// ---------------- main flash-attention kernel: 512 thr, QBLK=128, 8 waves
__global__ __launch_bounds__(512, 2) void fattn_main(
    const float* __restrict__ Qg, float* __restrict__ Og, const short* __restrict__ W)
{
  __shared__ __attribute__((aligned(16))) short buf[2][TILE_SH];   // 48 KB dbuf

  // big q-tiles dispatch first; bh%8 == XCD (KV image L2-resident per XCD)
  const int bid = blockIdx.x;
  const int bh = bid & 31;
  const int qt = (NQB - 1) - (bid >> 5);

  const int tid = threadIdx.x;
  const int w = tid >> 6, l = tid & 63;
  const int l15 = l & 15, lg = l >> 4;

  const short* Wb = W + (size_t)bh * NQT * TILE_SH;
  const float* Qb = Qg + (size_t)bh * S_LEN * DIM;
  float*       Ob = Og + (size_t)bh * S_LEN * DIM;

  const int qg = qt * 128 + w * 16 + l15;         // this lane's q row
  const float SC = 0.125f * 1.44269504088896f;    // (1/sqrt(64))*log2(e)

  // ---- hoist Q fragments (hi/lo split); B-frag: col=q(l15), k = lg*8 + j (+32s)
  s16x8 qh[2], ql[2];
#pragma unroll
  for (int s = 0; s < 2; ++s) {
    const float* qp = Qb + (size_t)qg * DIM + (lg << 3) + s * 32;
    float qv[8];
    *(f32x4*)&qv[0] = *(const f32x4*)qp;
    *(f32x4*)&qv[4] = *(const f32x4*)(qp + 4);
#pragma unroll
    for (int j = 0; j < 8; ++j) {
      short h = f2bf(qv[j]);
      qh[s][j] = h;
      ql[s][j] = f2bf(qv[j] - bf2f(h));
    }
  }

  f32x4 o[4];
#pragma unroll
  for (int d = 0; d < 4; ++d) o[d] = f32x4{0.f,0.f,0.f,0.f};
  float m = -INFINITY, lsum = 0.f;

  const int nt = 2 * qt + 2;                      // kv tiles staged by the block
  const int my_nt = nt - (w < 4 ? 1 : 0);         // last tile fully masked for w<4
  stage24(Wb, buf[0], w, l);
  __syncthreads();
  int cur = 0;

  const int src0 = l15 + ((lg & 1) << 5);         // P-shuffle source lanes
  const int src1 = src0 + 16;
  const bool hiH = (lg >= 2);

  for (int t = 0; t < nt; ++t) {
    if (t + 1 < nt) stage24(Wb + (size_t)(t + 1) * TILE_SH, buf[cur ^ 1], w, l);

    if (t < my_nt) {
      const short* bK  = buf[cur];
      const short* bKl = bK + 4096;
      const short* bVt = bK + 8192;

      // ---- QK^T (swapped: S^T = K·Q^T), hi/lo split -> ~fp32 scores
      f32x4 acc[4];
#pragma unroll
      for (int f = 0; f < 4; ++f) acc[f] = f32x4{0.f,0.f,0.f,0.f};
#pragma unroll
      for (int f = 0; f < 4; ++f) {
        const int kr = f * 16 + l15;
#pragma unroll
        for (int s = 0; s < 2; ++s) {
          const int dk = (((lg << 3) + (s << 5)) ^ swz(kr));
          s16x8 ah = *(const s16x8*)&bK [kr * DIM + dk];
          s16x8 al = *(const s16x8*)&bKl[kr * DIM + dk];
          acc[f] = MFMA_B16(ah, qh[s], acc[f]);
          acc[f] = MFMA_B16(ah, ql[s], acc[f]);
          acc[f] = MFMA_B16(al, qh[s], acc[f]);
        }
      }

      // ---- scale + causal mask (diag tile only); per-lane row max
      const bool diag = (t == my_nt - 1);
      const int kv0 = t * 64;
      float pm = -INFINITY;
#pragma unroll
      for (int f = 0; f < 4; ++f)
#pragma unroll
        for (int r = 0; r < 4; ++r) {
          float zz = acc[f][r] * SC;
          if (diag && (kv0 + f * 16 + (lg << 2) + r) > qg) zz = -INFINITY;
          acc[f][r] = zz;
          pm = fmaxf(pm, zz);
        }
      pm = fmaxf(pm, __shfl_xor(pm, 16));
      pm = fmaxf(pm, __shfl_xor(pm, 32));

      // ---- online softmax; rescale only when a new max appears
      if (!__all(pm <= m)) {
        const float mn = fmaxf(m, pm);
        const float al = EX2(m - mn);
        m = mn; lsum *= al;
#pragma unroll
        for (int d = 0; d < 4; ++d) o[d] *= al;
      }
      float rs = 0.f;
#pragma unroll
      for (int f = 0; f < 4; ++f)
#pragma unroll
        for (int r = 0; r < 4; ++r) {
          const float pv = EX2(acc[f][r] - m);
          acc[f][r] = pv;
          rs += pv;
        }
      rs += __shfl_xor(rs, 16);
      rs += __shfl_xor(rs, 32);
      lsum += rs;

      // ---- P: C-frag -> B-frag via 4-lane shuffles (no LDS barrier)
      unsigned U[4][2];
#pragma unroll
      for (int f = 0; f < 4; ++f) {
        U[f][0] = packbf(acc[f][0], acc[f][1]);
        U[f][1] = packbf(acc[f][2], acc[f][3]);
      }
#pragma unroll
      for (int s = 0; s < 2; ++s) {
        unsigned a0 = __shfl(U[2*s][0], src0), a1 = __shfl(U[2*s+1][0], src0);
        unsigned b0 = __shfl(U[2*s][1], src0), b1 = __shfl(U[2*s+1][1], src0);
        unsigned c0 = __shfl(U[2*s][0], src1), c1 = __shfl(U[2*s+1][0], src1);
        unsigned d0 = __shfl(U[2*s][1], src1), d1 = __shfl(U[2*s+1][1], src1);
        union { unsigned u[4]; s16x8 v; } pb;
        pb.u[0] = hiH ? a1 : a0;
        pb.u[1] = hiH ? b1 : b0;
        pb.u[2] = hiH ? c1 : c0;
        pb.u[3] = hiH ? d1 : d0;
        const int kv8 = (lg << 3) + (s << 5);
#pragma unroll
        for (int d = 0; d < 4; ++d) {
          const int dv = d * 16 + l15;
          s16x8 vf = *(const s16x8*)&bVt[dv * DIM + (kv8 ^ swz(dv))];
          o[d] = MFMA_B16(vf, pb.v, o[d]);
        }
      }
    }

    __syncthreads();    // drains prefetch vmcnt AFTER compute; guards dbuf reuse
    cur ^= 1;
  }

  // ---- epilogue
  const float inv = 1.0f / lsum;
#pragma unroll
  for (int d = 0; d < 4; ++d) {
    f32x4 ov;
#pragma unroll
    for (int r = 0; r < 4; ++r) ov[r] = o[d][r] * inv;
    *(f32x4*)(Ob + (size_t)qg * DIM + d * 16 + (lg << 2)) = ov;
  }
}

// ---------------- fallback (round-1 kernel, used only if ws too small) ----------------
#define QBLK  64
#define KVBLK 64
#define NPAIR (NQT/2)
#define NBLK  (NBH*NPAIR)

__global__ __launch_bounds__(256) void fattn_fb(
    const float* __restrict__ Qg, const float* __restrict__ Kg,
    const float* __restrict__ Vg, float* __restrict__ Og)
{
  __shared__ __attribute__((aligned(16))) short Khi[KVBLK*DIM];
  __shared__ __attribute__((aligned(16))) short Klo[KVBLK*DIM];
  __shared__ __attribute__((aligned(16))) short Vt [DIM*KVBLK];
  __shared__ __attribute__((aligned(16))) short Pl [4*16*KVBLK];

  int bid0 = blockIdx.x;
  int bid  = (bid0 & 7) * (NBLK/8) + (bid0 >> 3);
  int bh   = bid / NPAIR;
  int pr   = bid % NPAIR;
  const int tid = threadIdx.x;
  const int w = tid >> 6, l = tid & 63, l15 = l & 15, lg = l >> 4;
  const float* Qb = Qg + (size_t)bh * S_LEN * DIM;
  const float* Kb = Kg + (size_t)bh * S_LEN * DIM;
  const float* Vb = Vg + (size_t)bh * S_LEN * DIM;
  float*       Ob = Og + (size_t)bh * S_LEN * DIM;
  const float SC = 0.125f * 1.44269504088896f;

  for (int half = 0; half < 2; ++half) {
    const int qt = half ? (NQT - 1 - pr) : pr;
    const int qg = qt * QBLK + w * 16 + l15;
    s16x8 qh[2], ql[2];
#pragma unroll
    for (int s = 0; s < 2; ++s) {
      const float* qp = Qb + (size_t)qg * DIM + (lg << 3) + s * 32;
      float qv[8];
      *(f32x4*)&qv[0] = *(const f32x4*)qp;
      *(f32x4*)&qv[4] = *(const f32x4*)(qp + 4);
#pragma unroll
      for (int j = 0; j < 8; ++j) {
        short h = f2bf(qv[j]); qh[s][j] = h; ql[s][j] = f2bf(qv[j] - bf2f(h));
      }
    }
    f32x4 o[4];
#pragma unroll
    for (int d = 0; d < 4; ++d) o[d] = f32x4{0.f,0.f,0.f,0.f};
    float m = -INFINITY, lsum = 0.f;
    const int ntiles = qt + 1;
    for (int t = 0; t < ntiles; ++t) {
      const int kv0 = t * KVBLK;
      __syncthreads();
      {
        const int row = tid >> 4, c4 = (tid & 15) << 2;
#pragma unroll
        for (int i = 0; i < 4; ++i) {
          const int r = row + (i << 4);
          const f32x4 kv4 = *(const f32x4*)(Kb + (size_t)(kv0 + r) * DIM + c4);
          const f32x4 vv4 = *(const f32x4*)(Vb + (size_t)(kv0 + r) * DIM + c4);
          const int cs = c4 ^ swz(r);
          s16x4 kh, kl;
#pragma unroll
          for (int j = 0; j < 4; ++j) { short h = f2bf(kv4[j]); kh[j] = h; kl[j] = f2bf(kv4[j] - bf2f(h)); }
          *(s16x4*)&Khi[r * DIM + cs] = kh;
          *(s16x4*)&Klo[r * DIM + cs] = kl;
#pragma unroll
          for (int j = 0; j < 4; ++j) { const int dv = c4 + j; Vt[dv * KVBLK + (r ^ swz(dv))] = f2bf(vv4[j]); }
        }
      }
      __syncthreads();
      f32x4 acc[4];
#pragma unroll
      for (int f = 0; f < 4; ++f) acc[f] = f32x4{0.f,0.f,0.f,0.f};
#pragma unroll
      for (int f = 0; f < 4; ++f) {
        const int kr = f * 16 + l15;
#pragma unroll
        for (int s = 0; s < 2; ++s) {
          const int dk = (((lg << 3) + (s << 5)) ^ swz(kr));
          s16x8 ah = *(const s16x8*)&Khi[kr * DIM + dk];
          s16x8 al = *(const s16x8*)&Klo[kr * DIM + dk];
          acc[f] = MFMA_B16(ah, qh[s], acc[f]);
          acc[f] = MFMA_B16(ah, ql[s], acc[f]);
          acc[f] = MFMA_B16(al, qh[s], acc[f]);
        }
      }
      const bool diag = (t == qt);
      float z[4][4];
#pragma unroll
      for (int f = 0; f < 4; ++f)
#pragma unroll
        for (int r = 0; r < 4; ++r) {
          float zz = acc[f][r] * SC;
          if (diag && (kv0 + f * 16 + (lg << 2) + r) > qg) zz = -INFINITY;
          z[f][r] = zz;
        }
      float pm = z[0][0];
#pragma unroll
      for (int f = 0; f < 4; ++f)
#pragma unroll
        for (int r = 0; r < 4; ++r) pm = fmaxf(pm, z[f][r]);
      pm = fmaxf(pm, __shfl_xor(pm, 16));
      pm = fmaxf(pm, __shfl_xor(pm, 32));
      const float mn = fmaxf(m, pm);
      const float alpha = EX2(m - mn);
      float p[4][4]; float rs = 0.f;
#pragma unroll
      for (int f = 0; f < 4; ++f)
#pragma unroll
        for (int r = 0; r < 4; ++r) { const float pv = EX2(z[f][r] - mn); p[f][r] = pv; rs += pv; }
      rs += __shfl_xor(rs, 16);
      rs += __shfl_xor(rs, 32);
      lsum = lsum * alpha + rs;
      m = mn;
#pragma unroll
      for (int d = 0; d < 4; ++d) o[d] *= alpha;
      short* Pw = &Pl[w * 16 * KVBLK];
#pragma unroll
      for (int f = 0; f < 4; ++f) {
        s16x4 pk;
#pragma unroll
        for (int r = 0; r < 4; ++r) pk[r] = f2bf(p[f][r]);
        const int kvc = (f * 16 + (lg << 2)) ^ swz(l15);
        *(s16x4*)&Pw[l15 * KVBLK + kvc] = pk;
      }
#pragma unroll
      for (int s = 0; s < 2; ++s) {
        const int kv8 = (lg << 3) + s * 32;
        s16x8 pf = *(const s16x8*)&Pw[l15 * KVBLK + (kv8 ^ swz(l15))];
#pragma unroll
        for (int d = 0; d < 4; ++d) {
          const int dv = d * 16 + l15;
          s16x8 vf = *(const s16x8*)&Vt[dv * KVBLK + (kv8 ^ swz(dv))];
          o[d] = MFMA_B16(vf, pf, o[d]);
        }
      }
    }
    const float inv = 1.0f / lsum;
#pragma unroll
    for (int d = 0; d < 4; ++d) {
      f32x4 ov;
#pragma unroll
      for (int r = 0; r < 4; ++r) ov[r] = o[d][r] * inv;
      *(f32x4*)(Ob + (size_t)qg * DIM + d * 16 + (lg << 2)) = ov;
    }
  }
}

extern "C" void kernel_launch(void* const* d_in, const int* in_sizes, int n_in,
                              void* d_out, int out_size, void* d_ws, size_t ws_size,
                              hipStream_t stream) {
  const float* Q = (const float*)d_in[0];
  const float* K = (const float*)d_in[1];
  const float* V = (const float*)d_in[2];
  float* O = (float*)d_out;
  if (ws_size >= WS_NEED) {
    short* W = (short*)d_ws;
    prep_kv  <<<dim3(NBH * NQT), dim3(256), 0, stream>>>(K, V, W);
    fattn_main<<<dim3(NBH * NQB), dim3(512), 0, stream>>>(Q, O, W);
  } else {
    fattn_fb<<<dim3(NBLK), dim3(256), 0, stream>>>(Q, K, V, O);
  }
}

// Round 7
// 166.553 us; speedup vs baseline: 1.1836x; 1.0032x over previous
//
#include <hip/hip_runtime.h>
#include <hip/hip_bf16.h>

#define S_LEN 2048
#define DIM   64
#define NBH   32            // B*H
#define NQT   32            // kv tiles of 64
#define NQB   16            // q blocks of 128
#define TILE_SH 12288       // shorts per (bh,kvtile) image: Khi 4096 | Klo 4096 | Vt 4096
#define WS_NEED ((size_t)NBH * NQT * TILE_SH * sizeof(short))

typedef __attribute__((ext_vector_type(4))) float f32x4;
typedef __attribute__((ext_vector_type(8))) short s16x8;
typedef __attribute__((ext_vector_type(4))) short s16x4;

#define MFMA_B16(A,B,C) __builtin_amdgcn_mfma_f32_16x16x32_bf16(A,B,C,0,0,0)
#define EX2(x) __builtin_amdgcn_exp2f(x)

__device__ __forceinline__ short f2bf(float x){
  union{float f;unsigned u;} v; v.f=x;
  unsigned r = v.u + 0x7FFFu + ((v.u>>16)&1u);   // RNE
  return (short)(r>>16);
}
__device__ __forceinline__ float bf2f(short s){
  union{float f;unsigned u;} v; v.u=((unsigned)(unsigned short)s)<<16;
  return v.f;
}
__device__ __forceinline__ unsigned packbf(float a, float b){
  __hip_bfloat162 h = __float22bfloat162_rn(make_float2(a, b));   // v_cvt_pk_bf16_f32
  union { __hip_bfloat162 h; unsigned u; } cv; cv.h = h; return cv.u;
}
// XOR swizzle on element bits 3..5 (b128-safe)
__device__ __forceinline__ int swz(int row){
  return (((row&7) ^ ((row>>2)&7)) << 3);
}

// ---------------- pre-pass: K -> (Khi,Klo), V -> V^T, bf16, pre-swizzled tile images
__global__ __launch_bounds__(256) void prep_kv(
    const float* __restrict__ K, const float* __restrict__ V, short* __restrict__ W)
{
  __shared__ short Vl[4096];          // bf16 V^T image staging (8 KB)
  const int b  = blockIdx.x;          // = bh*32 + t
  const int bh = b >> 5, t = b & 31;
  const float* Kt = K + ((size_t)bh * S_LEN + t * 64) * DIM;
  const float* Vt = V + ((size_t)bh * S_LEN + t * 64) * DIM;
  short* Wt = W + (size_t)b * TILE_SH;
  const int tid = threadIdx.x;

  // --- K hi/lo: image[p] = hi/lo(K[r][(p&63)^swz(r)]) — coalesced f32x4 reads
#pragma unroll
  for (int i = 0; i < 2; ++i) {
    const int m = i * 256 + tid;      // chunk 0..511 (8 elems each)
    const int r = m >> 3, g = m & 7;
    const int c0 = (g << 3) ^ swz(r);
    float x[8];
    *(f32x4*)&x[0] = *(const f32x4*)(Kt + r * DIM + c0);
    *(f32x4*)&x[4] = *(const f32x4*)(Kt + r * DIM + c0 + 4);
    s16x8 hi, lo;
#pragma unroll
    for (int j = 0; j < 8; ++j) {
      short h = f2bf(x[j]);
      hi[j] = h;
      lo[j] = f2bf(x[j] - bf2f(h));
    }
    *(s16x8*)&Wt[m * 8]        = hi;
    *(s16x8*)&Wt[4096 + m * 8] = lo;
  }

  // --- V: coalesced row reads -> LDS transpose (u32-packed row pairs) -> coalesced out
  {
    const int r2 = (tid >> 3) << 1;         // even row: handles rows r2, r2+1
    const int cb = (tid & 7) << 3;          // 8-col chunk
    float x0[8], x1[8];
    *(f32x4*)&x0[0] = *(const f32x4*)(Vt + r2 * DIM + cb);
    *(f32x4*)&x0[4] = *(const f32x4*)(Vt + r2 * DIM + cb + 4);
    *(f32x4*)&x1[0] = *(const f32x4*)(Vt + (r2 + 1) * DIM + cb);
    *(f32x4*)&x1[4] = *(const f32x4*)(Vt + (r2 + 1) * DIM + cb + 4);
#pragma unroll
    for (int j = 0; j < 8; ++j) {
      const int c = cb + j;                 // = dv
      const int y = r2 ^ swz(c);            // even (swz touches bits 3..5 only)
      // image[dv*64+y] = V[y^swz(dv)][dv]; y -> row r2, y+1 -> row r2+1
      ((unsigned*)Vl)[(c * 64 + y) >> 1] = packbf(x0[j], x1[j]);
    }
  }
  __syncthreads();
#pragma unroll
  for (int i = 0; i < 2; ++i) {
    const int p = (i * 256 + tid) * 8;
    *(s16x8*)&Wt[8192 + p] = *(const s16x8*)&Vl[p];
  }
}

// ---------------- async stage: 24KB tile image -> LDS (linear; data pre-swizzled in ws)
__device__ __forceinline__ void stage24(const short* __restrict__ src, short* dst,
                                        int w, int l) {
#pragma unroll
  for (int q = 0; q < 3; ++q) {
    const int off = (q * 8 + w) << 10;            // 24 × 1KB chunks, 8 waves
    __builtin_amdgcn_global_load_lds(
        (const __attribute__((address_space(1))) unsigned*)((const char*)src + off + l * 16),
        (__attribute__((address_space(3))) unsigned*)((char*)dst + off),
        16, 0, 0);
  }
}

// ---- QK^T for one staged tile (swapped: S^T = K·Q^T), hi/lo split -> ~fp32 scores
__device__ __forceinline__ void qk_tile(f32x4 acc[4], const short* __restrict__ bK,
                                        const s16x8 qh[2], const s16x8 ql[2],
                                        int l15, int lg)
{
  const short* bKl = bK + 4096;
#pragma unroll
  for (int f = 0; f < 4; ++f) acc[f] = f32x4{0.f,0.f,0.f,0.f};
#pragma unroll
  for (int f = 0; f < 4; ++f) {
    const int kr = f * 16 + l15;
#pragma unroll
    for (int s = 0; s < 2; ++s) {
      const int dk = (((lg << 3) + (s << 5)) ^ swz(kr));
      s16x8 ah = *(const s16x8*)&bK [kr * DIM + dk];
      s16x8 al = *(const s16x8*)&bKl[kr * DIM + dk];
      acc[f] = MFMA_B16(ah, qh[s], acc[f]);
      acc[f] = MFMA_B16(ah, ql[s], acc[f]);
      acc[f] = MFMA_B16(al, qh[s], acc[f]);
    }
  }
}

// ---- online softmax on acc (scores -> p values in place), updates m, lsum, rescales o
__device__ __forceinline__ void sm_update(f32x4 acc[4], f32x4 o[4], float& m, float& lsum,
                                          int kv0, int qg, int lg, float SC)
{
  const bool anymask = (kv0 + 63 > qg);
  float pm = -INFINITY;
#pragma unroll
  for (int f = 0; f < 4; ++f)
#pragma unroll
    for (int r = 0; r < 4; ++r) {
      float zz = acc[f][r] * SC;
      if (anymask && (kv0 + f * 16 + (lg << 2) + r) > qg) zz = -INFINITY;
      acc[f][r] = zz;
      pm = fmaxf(pm, zz);
    }
  pm = fmaxf(pm, __shfl_xor(pm, 16));
  pm = fmaxf(pm, __shfl_xor(pm, 32));
  if (!__all(pm <= m)) {               // rescale only when a new max appears
    const float mn = fmaxf(m, pm);
    const float al = EX2(m - mn);
    m = mn; lsum *= al;
#pragma unroll
    for (int d = 0; d < 4; ++d) o[d] *= al;
  }
  float rs = 0.f;
#pragma unroll
  for (int f = 0; f < 4; ++f)
#pragma unroll
    for (int r = 0; r < 4; ++r) {
      const float pv = EX2(acc[f][r] - m);
      acc[f][r] = pv;
      rs += pv;
    }
  rs += __shfl_xor(rs, 16);
  rs += __shfl_xor(rs, 32);
  lsum += rs;
}

// ---- P (C-frag) -> B-frag via 4-lane shuffles, then O^T += V^T·P^T
__device__ __forceinline__ void pv_tile(const f32x4 p[4], f32x4 o[4],
                                        const short* __restrict__ bVt,
                                        int l15, int lg, int src0, int src1, bool hiH)
{
  unsigned U[4][2];
#pragma unroll
  for (int f = 0; f < 4; ++f) {
    U[f][0] = packbf(p[f][0], p[f][1]);
    U[f][1] = packbf(p[f][2], p[f][3]);
  }
#pragma unroll
  for (int s = 0; s < 2; ++s) {
    unsigned a0 = __shfl(U[2*s][0], src0), a1 = __shfl(U[2*s+1][0], src0);
    unsigned b0 = __shfl(U[2*s][1], src0), b1 = __shfl(U[2*s+1][1], src0);
    unsigned c0 = __shfl(U[2*s][0], src1), c1 = __shfl(U[2*s+1][0], src1);
    unsigned d0 = __shfl(U[2*s][1], src1), d1 = __shfl(U[2*s+1][1], src1);
    union { unsigned u[4]; s16x8 v; } pb;
    pb.u[0] = hiH ? a1 : a0;
    pb.u[1] = hiH ? b1 : b0;
    pb.u[2] = hiH ? c1 : c0;
    pb.u[3] = hiH ? d1 : d0;
    const int kv8 = (lg << 3) + (s << 5);
#pragma unroll
    for (int d = 0; d < 4; ++d) {
      const int dv = d * 16 + l15;
      s16x8 vf = *(const s16x8*)&bVt[dv * DIM + (kv8 ^ swz(dv))];
      o[d] = MFMA_B16(vf, pb.v, o[d]);
    }
  }
}

// ---------------- main: 512 thr, QBLK=128, 2-stage pipeline over 3 LDS buffers
__global__ __launch_bounds__(512, 4) void fattn_main(
    const float* __restrict__ Qg, float* __restrict__ Og, const short* __restrict__ W)
{
  __shared__ __attribute__((aligned(16))) short buf[3][TILE_SH];   // 72 KB

  // big q-tiles dispatch first; bh%8 == XCD (KV image L2-resident per XCD)
  const int bid = blockIdx.x;
  const int bh = bid & 31;
  const int qt = (NQB - 1) - (bid >> 5);

  const int tid = threadIdx.x;
  const int w = tid >> 6, l = tid & 63;
  const int l15 = l & 15, lg = l >> 4;

  const short* Wb = W + (size_t)bh * NQT * TILE_SH;
  const float* Qb = Qg + (size_t)bh * S_LEN * DIM;
  float*       Ob = Og + (size_t)bh * S_LEN * DIM;

  const int qg = qt * 128 + w * 16 + l15;         // this lane's q row
  const float SC = 0.125f * 1.44269504088896f;    // (1/sqrt(64))*log2(e)

  // ---- hoist Q fragments (hi/lo split); B-frag: col=q(l15), k = lg*8 + j (+32s)
  s16x8 qh[2], ql[2];
#pragma unroll
  for (int s = 0; s < 2; ++s) {
    const float* qp = Qb + (size_t)qg * DIM + (lg << 3) + s * 32;
    float qv[8];
    *(f32x4*)&qv[0] = *(const f32x4*)qp;
    *(f32x4*)&qv[4] = *(const f32x4*)(qp + 4);
#pragma unroll
    for (int j = 0; j < 8; ++j) {
      short h = f2bf(qv[j]);
      qh[s][j] = h;
      ql[s][j] = f2bf(qv[j] - bf2f(h));
    }
  }

  f32x4 o[4];
#pragma unroll
  for (int d = 0; d < 4; ++d) o[d] = f32x4{0.f,0.f,0.f,0.f};
  float m = -INFINITY, lsum = 0.f;

  const int src0 = l15 + ((lg & 1) << 5);         // P-shuffle source lanes
  const int src1 = src0 + 16;
  const bool hiH = (lg >= 2);

  const int nt = 2 * qt + 2;                      // kv tiles (>= 2)

  // ---- pipeline prologue: stage(0); drain; stage(1); QK(0); drain
  short* b0 = buf[0];
  short* b1 = buf[1];
  short* b2 = buf[2];
  stage24(Wb, b0, w, l);
  __syncthreads();
  stage24(Wb + TILE_SH, b1, w, l);
  f32x4 acc[4];
  qk_tile(acc, b0, qh, ql, l15, lg);
  __syncthreads();

  // ---- steady state: softmax(t) [VALU] overlaps QK(t+1) [MFMA]; stage(t+2) in flight
  for (int t = 0; t < nt - 1; ++t) {
    if (t + 2 < nt) stage24(Wb + (size_t)(t + 2) * TILE_SH, b2, w, l);
    sm_update(acc, o, m, lsum, t * 64, qg, lg, SC);          // p(t) in acc
    f32x4 acc2[4];
    qk_tile(acc2, b1, qh, ql, l15, lg);                      // scores(t+1), independent
    pv_tile(acc, o, b0 + 8192, l15, lg, src0, src1, hiH);    // O += P(t)·V(t)
#pragma unroll
    for (int f = 0; f < 4; ++f) acc[f] = acc2[f];
    short* tmp = b0; b0 = b1; b1 = b2; b2 = tmp;             // rotate buffers
    __syncthreads();    // drains stage(t+2); guards buffer reuse
  }
  // ---- tail: last tile (fully masked for w<4 -> p==0, harmless)
  sm_update(acc, o, m, lsum, (nt - 1) * 64, qg, lg, SC);
  pv_tile(acc, o, b0 + 8192, l15, lg, src0, src1, hiH);

  // ---- epilogue
  const float inv = 1.0f / lsum;
#pragma unroll
  for (int d = 0; d < 4; ++d) {
    f32x4 ov;
#pragma unroll
    for (int r = 0; r < 4; ++r) ov[r] = o[d][r] * inv;
    *(f32x4*)(Ob + (size_t)qg * DIM + d * 16 + (lg << 2)) = ov;
  }
}

// ---------------- fallback (round-1 kernel, used only if ws too small) ----------------
#define QBLK  64
#define KVBLK 64
#define NPAIR (NQT/2)
#define NBLK  (NBH*NPAIR)

__global__ __launch_bounds__(256) void fattn_fb(
    const float* __restrict__ Qg, const float* __restrict__ Kg,
    const float* __restrict__ Vg, float* __restrict__ Og)
{
  __shared__ __attribute__((aligned(16))) short Khi[KVBLK*DIM];
  __shared__ __attribute__((aligned(16))) short Klo[KVBLK*DIM];
  __shared__ __attribute__((aligned(16))) short Vt [DIM*KVBLK];
  __shared__ __attribute__((aligned(16))) short Pl [4*16*KVBLK];

  int bid0 = blockIdx.x;
  int bid  = (bid0 & 7) * (NBLK/8) + (bid0 >> 3);
  int bh   = bid / NPAIR;
  int pr   = bid % NPAIR;
  const int tid = threadIdx.x;
  const int w = tid >> 6, l = tid & 63, l15 = l & 15, lg = l >> 4;
  const float* Qb = Qg + (size_t)bh * S_LEN * DIM;
  const float* Kb = Kg + (size_t)bh * S_LEN * DIM;
  const float* Vb = Vg + (size_t)bh * S_LEN * DIM;
  float*       Ob = Og + (size_t)bh * S_LEN * DIM;
  const float SC = 0.125f * 1.44269504088896f;

  for (int half = 0; half < 2; ++half) {
    const int qt = half ? (NQT - 1 - pr) : pr;
    const int qg = qt * QBLK + w * 16 + l15;
    s16x8 qh[2], ql[2];
#pragma unroll
    for (int s = 0; s < 2; ++s) {
      const float* qp = Qb + (size_t)qg * DIM + (lg << 3) + s * 32;
      float qv[8];
      *(f32x4*)&qv[0] = *(const f32x4*)qp;
      *(f32x4*)&qv[4] = *(const f32x4*)(qp + 4);
#pragma unroll
      for (int j = 0; j < 8; ++j) {
        short h = f2bf(qv[j]); qh[s][j] = h; ql[s][j] = f2bf(qv[j] - bf2f(h));
      }
    }
    f32x4 o[4];
#pragma unroll
    for (int d = 0; d < 4; ++d) o[d] = f32x4{0.f,0.f,0.f,0.f};
    float m = -INFINITY, lsum = 0.f;
    const int ntiles = qt + 1;
    for (int t = 0; t < ntiles; ++t) {
      const int kv0 = t * KVBLK;
      __syncthreads();
      {
        const int row = tid >> 4, c4 = (tid & 15) << 2;
#pragma unroll
        for (int i = 0; i < 4; ++i) {
          const int r = row + (i << 4);
          const f32x4 kv4 = *(const f32x4*)(Kb + (size_t)(kv0 + r) * DIM + c4);
          const f32x4 vv4 = *(const f32x4*)(Vb + (size_t)(kv0 + r) * DIM + c4);
          const int cs = c4 ^ swz(r);
          s16x4 kh, kl;
#pragma unroll
          for (int j = 0; j < 4; ++j) { short h = f2bf(kv4[j]); kh[j] = h; kl[j] = f2bf(kv4[j] - bf2f(h)); }
          *(s16x4*)&Khi[r * DIM + cs] = kh;
          *(s16x4*)&Klo[r * DIM + cs] = kl;
#pragma unroll
          for (int j = 0; j < 4; ++j) { const int dv = c4 + j; Vt[dv * KVBLK + (r ^ swz(dv))] = f2bf(vv4[j]); }
        }
      }
      __syncthreads();
      f32x4 acc[4];
#pragma unroll
      for (int f = 0; f < 4; ++f) acc[f] = f32x4{0.f,0.f,0.f,0.f};
#pragma unroll
      for (int f = 0; f < 4; ++f) {
        const int kr = f * 16 + l15;
#pragma unroll
        for (int s = 0; s < 2; ++s) {
          const int dk = (((lg << 3) + (s << 5)) ^ swz(kr));
          s16x8 ah = *(const s16x8*)&Khi[kr * DIM + dk];
          s16x8 al = *(const s16x8*)&Klo[kr * DIM + dk];
          acc[f] = MFMA_B16(ah, qh[s], acc[f]);
          acc[f] = MFMA_B16(ah, ql[s], acc[f]);
          acc[f] = MFMA_B16(al, qh[s], acc[f]);
        }
      }
      const bool diag = (t == qt);
      float z[4][4];
#pragma unroll
      for (int f = 0; f < 4; ++f)
#pragma unroll
        for (int r = 0; r < 4; ++r) {
          float zz = acc[f][r] * SC;
          if (diag && (kv0 + f * 16 + (lg << 2) + r) > qg) zz = -INFINITY;
          z[f][r] = zz;
        }
      float pm = z[0][0];
#pragma unroll
      for (int f = 0; f < 4; ++f)
#pragma unroll
        for (int r = 0; r < 4; ++r) pm = fmaxf(pm, z[f][r]);
      pm = fmaxf(pm, __shfl_xor(pm, 16));
      pm = fmaxf(pm, __shfl_xor(pm, 32));
      const float mn = fmaxf(m, pm);
      const float alpha = EX2(m - mn);
      float p[4][4]; float rs = 0.f;
#pragma unroll
      for (int f = 0; f < 4; ++f)
#pragma unroll
        for (int r = 0; r < 4; ++r) { const float pv = EX2(z[f][r] - mn); p[f][r] = pv; rs += pv; }
      rs += __shfl_xor(rs, 16);
      rs += __shfl_xor(rs, 32);
      lsum = lsum * alpha + rs;
      m = mn;
#pragma unroll
      for (int d = 0; d < 4; ++d) o[d] *= alpha;
      short* Pw = &Pl[w * 16 * KVBLK];
#pragma unroll
      for (int f = 0; f < 4; ++f) {
        s16x4 pk;
#pragma unroll
        for (int r = 0; r < 4; ++r) pk[r] = f2bf(p[f][r]);
        const int kvc = (f * 16 + (lg << 2)) ^ swz(l15);
        *(s16x4*)&Pw[l15 * KVBLK + kvc] = pk;
      }
#pragma unroll
      for (int s = 0; s < 2; ++s) {
        const int kv8 = (lg << 3) + s * 32;
        s16x8 pf = *(const s16x8*)&Pw[l15 * KVBLK + (kv8 ^ swz(l15))];
#pragma unroll
        for (int d = 0; d < 4; ++d) {
          const int dv = d * 16 + l15;
          s16x8 vf = *(const s16x8*)&Vt[dv * KVBLK + (kv8 ^ swz(dv))];
          o[d] = MFMA_B16(vf, pf, o[d]);
        }
      }
    }
    const float inv = 1.0f / lsum;
#pragma unroll
    for (int d = 0; d < 4; ++d) {
      f32x4 ov;
#pragma unroll
      for (int r = 0; r < 4; ++r) ov[r] = o[d][r] * inv;
      *(f32x4*)(Ob + (size_t)qg * DIM + d * 16 + (lg << 2)) = ov;
    }
  }
}

extern "C" void kernel_launch(void* const* d_in, const int* in_sizes, int n_in,
                              void* d_out, int out_size, void* d_ws, size_t ws_size,
                              hipStream_t stream) {
  const float* Q = (const float*)d_in[0];
  const float* K = (const float*)d_in[1];
  const float* V = (const float*)d_in[2];
  float* O = (float*)d_out;
  if (ws_size >= WS_NEED) {
    short* W = (short*)d_ws;
    prep_kv  <<<dim3(NBH * NQT), dim3(256), 0, stream>>>(K, V, W);
    fattn_main<<<dim3(NBH * NQB), dim3(512), 0, stream>>>(Q, O, W);
  } else {
    fattn_fb<<<dim3(NBLK), dim3(256), 0, stream>>>(Q, K, V, O);
  }
}

// Round 9
// 163.776 us; speedup vs baseline: 1.2037x; 1.0170x over previous
//
#include <hip/hip_runtime.h>
#include <hip/hip_bf16.h>

#define S_LEN 2048
#define DIM   64
#define NBH   32            // B*H
#define NQT   32            // kv tiles of 64
#define NQB   16            // q blocks of 128
#define TILE_SH 12288       // shorts per (bh,kvtile) image: Khi 4096 | Klo 4096 | Vt 4096
#define WS_NEED ((size_t)NBH * NQT * TILE_SH * sizeof(short))

typedef __attribute__((ext_vector_type(4))) float f32x4;
typedef __attribute__((ext_vector_type(8))) short s16x8;
typedef __attribute__((ext_vector_type(4))) short s16x4;

#define MFMA_B16(A,B,C) __builtin_amdgcn_mfma_f32_16x16x32_bf16(A,B,C,0,0,0)
#define EX2(x) __builtin_amdgcn_exp2f(x)

__device__ __forceinline__ short f2bf(float x){
  union{float f;unsigned u;} v; v.f=x;
  unsigned r = v.u + 0x7FFFu + ((v.u>>16)&1u);   // RNE
  return (short)(r>>16);
}
__device__ __forceinline__ float bf2f(short s){
  union{float f;unsigned u;} v; v.u=((unsigned)(unsigned short)s)<<16;
  return v.f;
}
__device__ __forceinline__ unsigned packbf(float a, float b){
  __hip_bfloat162 h = __float22bfloat162_rn(make_float2(a, b));   // v_cvt_pk_bf16_f32
  union { __hip_bfloat162 h; unsigned u; } cv; cv.h = h; return cv.u;
}
// XOR swizzle on element bits 3..5 (b128-safe)
__device__ __forceinline__ int swz(int row){
  return (((row&7) ^ ((row>>2)&7)) << 3);
}

// ---------------- pre-pass: K -> (Khi,Klo), V -> V^T, bf16, pre-swizzled tile images
__global__ __launch_bounds__(256) void prep_kv(
    const float* __restrict__ K, const float* __restrict__ V, short* __restrict__ W)
{
  __shared__ short Vl[4096];          // bf16 V^T image staging (8 KB)
  const int b  = blockIdx.x;          // = bh*32 + t
  const int bh = b >> 5, t = b & 31;
  const float* Kt = K + ((size_t)bh * S_LEN + t * 64) * DIM;
  const float* Vt = V + ((size_t)bh * S_LEN + t * 64) * DIM;
  short* Wt = W + (size_t)b * TILE_SH;
  const int tid = threadIdx.x;

  // --- K hi/lo: image[p] = hi/lo(K[r][(p&63)^swz(r)]) — coalesced f32x4 reads
#pragma unroll
  for (int i = 0; i < 2; ++i) {
    const int m = i * 256 + tid;      // chunk 0..511 (8 elems each)
    const int r = m >> 3, g = m & 7;
    const int c0 = (g << 3) ^ swz(r);
    float x[8];
    *(f32x4*)&x[0] = *(const f32x4*)(Kt + r * DIM + c0);
    *(f32x4*)&x[4] = *(const f32x4*)(Kt + r * DIM + c0 + 4);
    s16x8 hi, lo;
#pragma unroll
    for (int j = 0; j < 8; ++j) {
      short h = f2bf(x[j]);
      hi[j] = h;
      lo[j] = f2bf(x[j] - bf2f(h));
    }
    *(s16x8*)&Wt[m * 8]        = hi;
    *(s16x8*)&Wt[4096 + m * 8] = lo;
  }

  // --- V: coalesced row reads -> LDS transpose (u32-packed row pairs) -> coalesced out
  {
    const int r2 = (tid >> 3) << 1;         // even row: handles rows r2, r2+1
    const int cb = (tid & 7) << 3;          // 8-col chunk
    float x0[8], x1[8];
    *(f32x4*)&x0[0] = *(const f32x4*)(Vt + r2 * DIM + cb);
    *(f32x4*)&x0[4] = *(const f32x4*)(Vt + r2 * DIM + cb + 4);
    *(f32x4*)&x1[0] = *(const f32x4*)(Vt + (r2 + 1) * DIM + cb);
    *(f32x4*)&x1[4] = *(const f32x4*)(Vt + (r2 + 1) * DIM + cb + 4);
#pragma unroll
    for (int j = 0; j < 8; ++j) {
      const int c = cb + j;                 // = dv
      const int y = r2 ^ swz(c);            // even (swz touches bits 3..5 only)
      // image[dv*64+y] = V[y^swz(dv)][dv]; y -> row r2, y+1 -> row r2+1
      ((unsigned*)Vl)[(c * 64 + y) >> 1] = packbf(x0[j], x1[j]);
    }
  }
  __syncthreads();
#pragma unroll
  for (int i = 0; i < 2; ++i) {
    const int p = (i * 256 + tid) * 8;
    *(s16x8*)&Wt[8192 + p] = *(const s16x8*)&Vl[p];
  }
}

// ---------------- async stage: 24KB tile image -> LDS (linear; data pre-swizzled in ws)
__device__ __forceinline__ void stage24(const short* __restrict__ src, short* dst,
                                        int w, int l) {
#pragma unroll
  for (int q = 0; q < 3; ++q) {
    const int off = (q * 8 + w) << 10;            // 24 × 1KB chunks, 8 waves
    __builtin_amdgcn_global_load_lds(
        (const __attribute__((address_space(1))) unsigned*)((const char*)src + off + l * 16),
        (__attribute__((address_space(3))) unsigned*)((char*)dst + off),
        16, 0, 0);
  }
}

// ---- QK^T for one staged tile (swapped: S^T = K·Q^T), hi/lo split -> ~fp32 scores
__device__ __forceinline__ void qk_tile(f32x4 acc[4], const short* __restrict__ bK,
                                        const s16x8 qh[2], const s16x8 ql[2],
                                        int l15, int lg)
{
  const short* bKl = bK + 4096;
#pragma unroll
  for (int f = 0; f < 4; ++f) acc[f] = f32x4{0.f,0.f,0.f,0.f};
#pragma unroll
  for (int f = 0; f < 4; ++f) {
    const int kr = f * 16 + l15;
#pragma unroll
    for (int s = 0; s < 2; ++s) {
      const int dk = (((lg << 3) + (s << 5)) ^ swz(kr));
      s16x8 ah = *(const s16x8*)&bK [kr * DIM + dk];
      s16x8 al = *(const s16x8*)&bKl[kr * DIM + dk];
      acc[f] = MFMA_B16(ah, qh[s], acc[f]);
      acc[f] = MFMA_B16(ah, ql[s], acc[f]);
      acc[f] = MFMA_B16(al, qh[s], acc[f]);
    }
  }
}

// ---- online softmax on acc (scores -> p values in place), updates m, lsum, rescales o
__device__ __forceinline__ void sm_update(f32x4 acc[4], f32x4 o[4], float& m, float& lsum,
                                          int kv0, int qg, int lg, float SC)
{
  const bool anymask = (kv0 + 63 > qg);
  float pm = -INFINITY;
#pragma unroll
  for (int f = 0; f < 4; ++f)
#pragma unroll
    for (int r = 0; r < 4; ++r) {
      float zz = acc[f][r] * SC;
      if (anymask && (kv0 + f * 16 + (lg << 2) + r) > qg) zz = -INFINITY;
      acc[f][r] = zz;
      pm = fmaxf(pm, zz);
    }
  pm = fmaxf(pm, __shfl_xor(pm, 16));
  pm = fmaxf(pm, __shfl_xor(pm, 32));
  if (!__all(pm <= m)) {               // rescale only when a new max appears
    const float mn = fmaxf(m, pm);
    const float al = EX2(m - mn);
    m = mn; lsum *= al;
#pragma unroll
    for (int d = 0; d < 4; ++d) o[d] *= al;
  }
  float rs = 0.f;
#pragma unroll
  for (int f = 0; f < 4; ++f)
#pragma unroll
    for (int r = 0; r < 4; ++r) {
      const float pv = EX2(acc[f][r] - m);
      acc[f][r] = pv;
      rs += pv;
    }
  rs += __shfl_xor(rs, 16);
  rs += __shfl_xor(rs, 32);
  lsum += rs;
}

// ---- P (C-frag) -> B-frag via 4-lane shuffles, then O^T += V^T·P^T
__device__ __forceinline__ void pv_tile(const f32x4 p[4], f32x4 o[4],
                                        const short* __restrict__ bVt,
                                        int l15, int lg, int src0, int src1, bool hiH)
{
  unsigned U[4][2];
#pragma unroll
  for (int f = 0; f < 4; ++f) {
    U[f][0] = packbf(p[f][0], p[f][1]);
    U[f][1] = packbf(p[f][2], p[f][3]);
  }
#pragma unroll
  for (int s = 0; s < 2; ++s) {
    unsigned a0 = __shfl(U[2*s][0], src0), a1 = __shfl(U[2*s+1][0], src0);
    unsigned b0 = __shfl(U[2*s][1], src0), b1 = __shfl(U[2*s+1][1], src0);
    unsigned c0 = __shfl(U[2*s][0], src1), c1 = __shfl(U[2*s+1][0], src1);
    unsigned d0 = __shfl(U[2*s][1], src1), d1 = __shfl(U[2*s+1][1], src1);
    union { unsigned u[4]; s16x8 v; } pb;
    pb.u[0] = hiH ? a1 : a0;
    pb.u[1] = hiH ? b1 : b0;
    pb.u[2] = hiH ? c1 : c0;
    pb.u[3] = hiH ? d1 : d0;
    const int kv8 = (lg << 3) + (s << 5);
#pragma unroll
    for (int d = 0; d < 4; ++d) {
      const int dv = d * 16 + l15;
      s16x8 vf = *(const s16x8*)&bVt[dv * DIM + (kv8 ^ swz(dv))];
      o[d] = MFMA_B16(vf, pb.v, o[d]);
    }
  }
}

// ---------------- main: 512 thr, QBLK=128, 2-stage pipeline over 3 LDS buffers
__global__ __launch_bounds__(512, 4) void fattn_main(
    const float* __restrict__ Qg, float* __restrict__ Og, const short* __restrict__ W)
{
  __shared__ __attribute__((aligned(16))) short buf[3][TILE_SH];   // 72 KB

  // Balanced CU pairing: under XCD round-robin, blocks bid and bid+256 land on
  // the same CU. qt(idx)+qt(idx+8) == 15 -> every CU gets exactly 34 tile-units
  // (was 48-4*(idx) worst case: 40% tail imbalance). Heavy half dispatches first.
  // bh = bid&31 keeps each bh's KV images on one XCD's L2.
  const int bid = blockIdx.x;
  const int bh = bid & 31;
  const int idx = bid >> 5;
  const int qt = (idx < 8) ? (15 - idx) : (idx - 8);

  const int tid = threadIdx.x;
  const int w = tid >> 6, l = tid & 63;
  const int l15 = l & 15, lg = l >> 4;

  const short* Wb = W + (size_t)bh * NQT * TILE_SH;
  const float* Qb = Qg + (size_t)bh * S_LEN * DIM;
  float*       Ob = Og + (size_t)bh * S_LEN * DIM;

  const int qg = qt * 128 + w * 16 + l15;         // this lane's q row
  const float SC = 0.125f * 1.44269504088896f;    // (1/sqrt(64))*log2(e)

  // ---- hoist Q fragments (hi/lo split); B-frag: col=q(l15), k = lg*8 + j (+32s)
  s16x8 qh[2], ql[2];
#pragma unroll
  for (int s = 0; s < 2; ++s) {
    const float* qp = Qb + (size_t)qg * DIM + (lg << 3) + s * 32;
    float qv[8];
    *(f32x4*)&qv[0] = *(const f32x4*)qp;
    *(f32x4*)&qv[4] = *(const f32x4*)(qp + 4);
#pragma unroll
    for (int j = 0; j < 8; ++j) {
      short h = f2bf(qv[j]);
      qh[s][j] = h;
      ql[s][j] = f2bf(qv[j] - bf2f(h));
    }
  }

  f32x4 o[4];
#pragma unroll
  for (int d = 0; d < 4; ++d) o[d] = f32x4{0.f,0.f,0.f,0.f};
  float m = -INFINITY, lsum = 0.f;

  const int src0 = l15 + ((lg & 1) << 5);         // P-shuffle source lanes
  const int src1 = src0 + 16;
  const bool hiH = (lg >= 2);

  const int nt = 2 * qt + 2;                      // kv tiles (>= 2)

  // ---- pipeline prologue: stage(0); drain; stage(1); QK(0); drain
  short* b0 = buf[0];
  short* b1 = buf[1];
  short* b2 = buf[2];
  stage24(Wb, b0, w, l);
  __syncthreads();
  stage24(Wb + TILE_SH, b1, w, l);
  f32x4 acc[4];
  qk_tile(acc, b0, qh, ql, l15, lg);
  __syncthreads();

  // ---- steady state: softmax(t) [VALU] overlaps QK(t+1) [MFMA]; stage(t+2) in flight
  for (int t = 0; t < nt - 1; ++t) {
    if (t + 2 < nt) stage24(Wb + (size_t)(t + 2) * TILE_SH, b2, w, l);
    sm_update(acc, o, m, lsum, t * 64, qg, lg, SC);          // p(t) in acc
    f32x4 acc2[4];
    qk_tile(acc2, b1, qh, ql, l15, lg);                      // scores(t+1), independent
    pv_tile(acc, o, b0 + 8192, l15, lg, src0, src1, hiH);    // O += P(t)·V(t)
#pragma unroll
    for (int f = 0; f < 4; ++f) acc[f] = acc2[f];
    short* tmp = b0; b0 = b1; b1 = b2; b2 = tmp;             // rotate buffers
    __syncthreads();    // drains stage(t+2); guards buffer reuse
  }
  // ---- tail: last tile (fully masked for w<4 -> p==0, harmless)
  sm_update(acc, o, m, lsum, (nt - 1) * 64, qg, lg, SC);
  pv_tile(acc, o, b0 + 8192, l15, lg, src0, src1, hiH);

  // ---- epilogue
  const float inv = 1.0f / lsum;
#pragma unroll
  for (int d = 0; d < 4; ++d) {
    f32x4 ov;
#pragma unroll
    for (int r = 0; r < 4; ++r) ov[r] = o[d][r] * inv;
    *(f32x4*)(Ob + (size_t)qg * DIM + d * 16 + (lg << 2)) = ov;
  }
}

// ---------------- fallback (round-1 kernel, used only if ws too small) ----------------
#define QBLK  64
#define KVBLK 64
#define NPAIR (NQT/2)
#define NBLK  (NBH*NPAIR)

__global__ __launch_bounds__(256) void fattn_fb(
    const float* __restrict__ Qg, const float* __restrict__ Kg,
    const float* __restrict__ Vg, float* __restrict__ Og)
{
  __shared__ __attribute__((aligned(16))) short Khi[KVBLK*DIM];
  __shared__ __attribute__((aligned(16))) short Klo[KVBLK*DIM];
  __shared__ __attribute__((aligned(16))) short Vt [DIM*KVBLK];
  __shared__ __attribute__((aligned(16))) short Pl [4*16*KVBLK];

  int bid0 = blockIdx.x;
  int bid  = (bid0 & 7) * (NBLK/8) + (bid0 >> 3);
  int bh   = bid / NPAIR;
  int pr   = bid % NPAIR;
  const int tid = threadIdx.x;
  const int w = tid >> 6, l = tid & 63, l15 = l & 15, lg = l >> 4;
  const float* Qb = Qg + (size_t)bh * S_LEN * DIM;
  const float* Kb = Kg + (size_t)bh * S_LEN * DIM;
  const float* Vb = Vg + (size_t)bh * S_LEN * DIM;
  float*       Ob = Og + (size_t)bh * S_LEN * DIM;
  const float SC = 0.125f * 1.44269504088896f;

  for (int half = 0; half < 2; ++half) {
    const int qt = half ? (NQT - 1 - pr) : pr;
    const int qg = qt * QBLK + w * 16 + l15;
    s16x8 qh[2], ql[2];
#pragma unroll
    for (int s = 0; s < 2; ++s) {
      const float* qp = Qb + (size_t)qg * DIM + (lg << 3) + s * 32;
      float qv[8];
      *(f32x4*)&qv[0] = *(const f32x4*)qp;
      *(f32x4*)&qv[4] = *(const f32x4*)(qp + 4);
#pragma unroll
      for (int j = 0; j < 8; ++j) {
        short h = f2bf(qv[j]); qh[s][j] = h; ql[s][j] = f2bf(qv[j] - bf2f(h));
      }
    }
    f32x4 o[4];
#pragma unroll
    for (int d = 0; d < 4; ++d) o[d] = f32x4{0.f,0.f,0.f,0.f};
    float m = -INFINITY, lsum = 0.f;
    const int ntiles = qt + 1;
    for (int t = 0; t < ntiles; ++t) {
      const int kv0 = t * KVBLK;
      __syncthreads();
      {
        const int row = tid >> 4, c4 = (tid & 15) << 2;
#pragma unroll
        for (int i = 0; i < 4; ++i) {
          const int r = row + (i << 4);
          const f32x4 kv4 = *(const f32x4*)(Kb + (size_t)(kv0 + r) * DIM + c4);
          const f32x4 vv4 = *(const f32x4*)(Vb + (size_t)(kv0 + r) * DIM + c4);
          const int cs = c4 ^ swz(r);
          s16x4 kh, kl;
#pragma unroll
          for (int j = 0; j < 4; ++j) { short h = f2bf(kv4[j]); kh[j] = h; kl[j] = f2bf(kv4[j] - bf2f(h)); }
          *(s16x4*)&Khi[r * DIM + cs] = kh;
          *(s16x4*)&Klo[r * DIM + cs] = kl;
#pragma unroll
          for (int j = 0; j < 4; ++j) { const int dv = c4 + j; Vt[dv * KVBLK + (r ^ swz(dv))] = f2bf(vv4[j]); }
        }
      }
      __syncthreads();
      f32x4 acc[4];
#pragma unroll
      for (int f = 0; f < 4; ++f) acc[f] = f32x4{0.f,0.f,0.f,0.f};
#pragma unroll
      for (int f = 0; f < 4; ++f) {
        const int kr = f * 16 + l15;
#pragma unroll
        for (int s = 0; s < 2; ++s) {
          const int dk = (((lg << 3) + (s << 5)) ^ swz(kr));
          s16x8 ah = *(const s16x8*)&Khi[kr * DIM + dk];
          s16x8 al = *(const s16x8*)&Klo[kr * DIM + dk];
          acc[f] = MFMA_B16(ah, qh[s], acc[f]);
          acc[f] = MFMA_B16(ah, ql[s], acc[f]);
          acc[f] = MFMA_B16(al, qh[s], acc[f]);
        }
      }
      const bool diag = (t == qt);
      float z[4][4];
#pragma unroll
      for (int f = 0; f < 4; ++f)
#pragma unroll
        for (int r = 0; r < 4; ++r) {
          float zz = acc[f][r] * SC;
          if (diag && (kv0 + f * 16 + (lg << 2) + r) > qg) zz = -INFINITY;
          z[f][r] = zz;
        }
      float pm = z[0][0];
#pragma unroll
      for (int f = 0; f < 4; ++f)
#pragma unroll
        for (int r = 0; r < 4; ++r) pm = fmaxf(pm, z[f][r]);
      pm = fmaxf(pm, __shfl_xor(pm, 16));
      pm = fmaxf(pm, __shfl_xor(pm, 32));
      const float mn = fmaxf(m, pm);
      const float alpha = EX2(m - mn);
      float p[4][4]; float rs = 0.f;
#pragma unroll
      for (int f = 0; f < 4; ++f)
#pragma unroll
        for (int r = 0; r < 4; ++r) { const float pv = EX2(z[f][r] - mn); p[f][r] = pv; rs += pv; }
      rs += __shfl_xor(rs, 16);
      rs += __shfl_xor(rs, 32);
      lsum = lsum * alpha + rs;
      m = mn;
#pragma unroll
      for (int d = 0; d < 4; ++d) o[d] *= alpha;
      short* Pw = &Pl[w * 16 * KVBLK];
#pragma unroll
      for (int f = 0; f < 4; ++f) {
        s16x4 pk;
#pragma unroll
        for (int r = 0; r < 4; ++r) pk[r] = f2bf(p[f][r]);
        const int kvc = (f * 16 + (lg << 2)) ^ swz(l15);
        *(s16x4*)&Pw[l15 * KVBLK + kvc] = pk;
      }
#pragma unroll
      for (int s = 0; s < 2; ++s) {
        const int kv8 = (lg << 3) + s * 32;
        s16x8 pf = *(const s16x8*)&Pw[l15 * KVBLK + (kv8 ^ swz(l15))];
#pragma unroll
        for (int d = 0; d < 4; ++d) {
          const int dv = d * 16 + l15;
          s16x8 vf = *(const s16x8*)&Vt[dv * KVBLK + (kv8 ^ swz(dv))];
          o[d] = MFMA_B16(vf, pf, o[d]);
        }
      }
    }
    const float inv = 1.0f / lsum;
#pragma unroll
    for (int d = 0; d < 4; ++d) {
      f32x4 ov;
#pragma unroll
      for (int r = 0; r < 4; ++r) ov[r] = o[d][r] * inv;
      *(f32x4*)(Ob + (size_t)qg * DIM + d * 16 + (lg << 2)) = ov;
    }
  }
}

extern "C" void kernel_launch(void* const* d_in, const int* in_sizes, int n_in,
                              void* d_out, int out_size, void* d_ws, size_t ws_size,
                              hipStream_t stream) {
  const float* Q = (const float*)d_in[0];
  const float* K = (const float*)d_in[1];
  const float* V = (const float*)d_in[2];
  float* O = (float*)d_out;
  if (ws_size >= WS_NEED) {
    short* W = (short*)d_ws;
    prep_kv  <<<dim3(NBH * NQT), dim3(256), 0, stream>>>(K, V, W);
    fattn_main<<<dim3(NBH * NQB), dim3(512), 0, stream>>>(Q, O, W);
  } else {
    fattn_fb<<<dim3(NBLK), dim3(256), 0, stream>>>(Q, K, V, O);
  }
}